// Round 15
// baseline (267.883 us; speedup 1.0000x reference)
//
#include <hip/hip_runtime.h>

typedef __attribute__((ext_vector_type(8))) short bf16x8;
typedef __attribute__((ext_vector_type(4))) float f32x4;
typedef __attribute__((ext_vector_type(4))) unsigned short u16x4;

#define GPTR(p) (const __attribute__((address_space(1))) void*)(p)
#define LPTR(p) (__attribute__((address_space(3))) void*)(p)

static __device__ __forceinline__ unsigned short f2bf(float f) {
  union { float f; unsigned int u; } x; x.f = f;
  unsigned int u = x.u;
  unsigned int r = (u + 0x7fffu + ((u >> 16) & 1u)) >> 16;
  return (unsigned short)r;
}
static __device__ __forceinline__ float bf2f(unsigned short h) {
  union { unsigned int u; float f; } x; x.u = ((unsigned int)h) << 16;
  return x.f;
}
static __device__ __forceinline__ f32x4 f32x4_zero() {
  f32x4 z = {0.f, 0.f, 0.f, 0.f}; return z;
}
static __device__ __forceinline__ unsigned int cvt_pk_bf16(float lo, float hi) {
  unsigned int r;
  asm("v_cvt_pk_bf16_f32 %0, %1, %2" : "=v"(r) : "v"(lo), "v"(hi));
  return r;
}

// ---------------------------------------------------------------- converts + RoPE table, one launch
__global__ void convert_all(const float* __restrict__ x,  const float* __restrict__ wq,
                            const float* __restrict__ wk, const float* __restrict__ wv,
                            const float* __restrict__ wo,
                            unsigned short* __restrict__ xb,
                            unsigned short* __restrict__ wqkvb,
                            unsigned short* __restrict__ wob,
                            float2* __restrict__ ctab) {
  const int stride = gridDim.x * blockDim.x;
  for (int i = blockIdx.x * blockDim.x + threadIdx.x; i < 4784128; i += stride) {
    if (i >= 4718592) {
      const int t = i - 4718592;         // 65536 table entries
      const int s = t >> 5, d = t & 31;
      float invf = exp2f(-(float)d * (13.287712379549449f / 32.0f));
      float a = (float)s * invf;
      ctab[t] = make_float2(cosf(a), sinf(a));
      continue;
    }
    const float* src; unsigned short* dst; int off;
    if (i < 2097152)      { src = x;  dst = xb;              off = i; }
    else if (i < 3145728) { src = wq; dst = wqkvb;           off = i - 2097152; }
    else if (i < 3407872) { src = wk; dst = wqkvb + 4194304; off = i - 3145728; }
    else if (i < 3670016) { src = wv; dst = wqkvb + 5242880; off = i - 3407872; }
    else                  { src = wo; dst = wob;             off = i - 3670016; }
    float4 v = ((const float4*)src)[off];
    u16x4 o;
    o.x = f2bf(v.x); o.y = f2bf(v.y); o.z = f2bf(v.z); o.w = f2bf(v.w);
    *(u16x4*)(dst + (size_t)off * 4) = o;
  }
}

// ---------------------------------------------------------------- 8-wave 4-phase GEMM C = A @ B^T
template<int FM, int OUT_BF16, int ROPE>
__global__ __launch_bounds__(512, 2) void gemm8p(const unsigned short* __restrict__ A,
                                                 const unsigned short* __restrict__ B,
                                                 void* __restrict__ Cv,
                                                 int M, int N, int K, int nbx,
                                                 const float2* __restrict__ ctab) {
  constexpr int BM = FM * 32;
  constexpr int MH = FM / 2;
  constexpr int ABYTES = BM * 128;      // per buffer
  constexpr int BBYTES = 256 * 128;
  __shared__ __align__(16) char lds_all[2 * ABYTES + 2 * BBYTES];
  char* lsA = lds_all;
  char* lsB = lds_all + 2 * ABYTES;

  const int tid = threadIdx.x;
  const int wave = tid >> 6, lane = tid & 63;
  const int fq = lane >> 4, fr = lane & 15;
  const int wr = wave >> 2, wc = wave & 3;

  const int nwg = gridDim.x;
  const int q8 = nwg >> 3;
  const int sw = (blockIdx.x & 7) * q8 + (blockIdx.x >> 3);
  const int by = sw / nbx;
  const int bx = sw - by * nbx;
  const int m0 = by * BM, n0 = bx * 256;

  const int arow = tid >> 3;
  const int scol = (((tid & 7) ^ (arow & 7)) << 4);   // pre-swizzled source col byte

#define STAGE_A(bufv, kt, h)                                                                  \
  do {                                                                                        \
    const char* src_ = (const char*)A + ((size_t)(m0 + (h) * 128 + arow) * K + (kt) * 64) * 2 + scol; \
    char* dst_ = lsA + (bufv) * ABYTES + (h) * 16384 + tid * 16;                              \
    __builtin_amdgcn_global_load_lds(GPTR(src_), LPTR(dst_), 16, 0, 0);                       \
    __builtin_amdgcn_global_load_lds(GPTR(src_ + (size_t)64 * K * 2), LPTR(dst_ + 8192), 16, 0, 0); \
  } while (0)
#define STAGE_B(bufv, kt, h)                                                                  \
  do {                                                                                        \
    const char* src_ = (const char*)B + ((size_t)(n0 + (h) * 128 + arow) * K + (kt) * 64) * 2 + scol; \
    char* dst_ = lsB + (bufv) * BBYTES + (h) * 16384 + tid * 16;                              \
    __builtin_amdgcn_global_load_lds(GPTR(src_), LPTR(dst_), 16, 0, 0);                       \
    __builtin_amdgcn_global_load_lds(GPTR(src_ + (size_t)64 * K * 2), LPTR(dst_ + 8192), 16, 0, 0); \
  } while (0)

  f32x4 acc[FM][4];
#pragma unroll
  for (int i = 0; i < FM; ++i)
#pragma unroll
    for (int j = 0; j < 4; ++j) acc[i][j] = f32x4_zero();

#define PHASE(p)                                                                              \
  do {                                                                                        \
    constexpr int mh = (p) >> 1, nh = (p) & 1;                                                \
    bf16x8 af[MH][2], bfv[2][2];                                                              \
    _Pragma("unroll") for (int m = 0; m < MH; ++m) {                                          \
      const int rowA = wr * FM * 16 + mh * MH * 16 + m * 16 + fr;                             \
      const char* pa = lsA + buf * ABYTES + (rowA >> 7) * 16384 + (rowA & 127) * 128;         \
      const int sz = (rowA & 7) << 4;                                                         \
      af[m][0] = *(const bf16x8*)(pa + ((fq * 16) ^ sz));                                     \
      af[m][1] = *(const bf16x8*)(pa + ((64 + fq * 16) ^ sz));                                \
    }                                                                                         \
    _Pragma("unroll") for (int n = 0; n < 2; ++n) {                                           \
      const int rowB = wc * 64 + nh * 32 + n * 16 + fr;                                       \
      const char* pb = lsB + buf * BBYTES + (rowB >> 7) * 16384 + (rowB & 127) * 128;         \
      const int sz = (rowB & 7) << 4;                                                         \
      bfv[n][0] = *(const bf16x8*)(pb + ((fq * 16) ^ sz));                                    \
      bfv[n][1] = *(const bf16x8*)(pb + ((64 + fq * 16) ^ sz));                               \
    }                                                                                         \
    asm volatile("s_waitcnt lgkmcnt(0)" ::: "memory");                                        \
    __builtin_amdgcn_sched_barrier(0);                                                        \
    __builtin_amdgcn_s_setprio(1);                                                            \
    _Pragma("unroll") for (int m = 0; m < MH; ++m)                                            \
      _Pragma("unroll") for (int n = 0; n < 2; ++n) {                                         \
        acc[mh * MH + m][nh * 2 + n] =                                                        \
            __builtin_amdgcn_mfma_f32_16x16x32_bf16(af[m][0], bfv[n][0], acc[mh * MH + m][nh * 2 + n], 0, 0, 0); \
        acc[mh * MH + m][nh * 2 + n] =                                                        \
            __builtin_amdgcn_mfma_f32_16x16x32_bf16(af[m][1], bfv[n][1], acc[mh * MH + m][nh * 2 + n], 0, 0, 0); \
      }                                                                                       \
    __builtin_amdgcn_s_setprio(0);                                                            \
  } while (0)

  const int NT = K >> 6;

  STAGE_A(0, 0, 0);
  if constexpr (FM == 8) STAGE_A(0, 0, 1);
  STAGE_B(0, 0, 0);
  STAGE_B(0, 0, 1);
  asm volatile("s_waitcnt vmcnt(0)" ::: "memory");
  __builtin_amdgcn_s_barrier();

  int buf = 0;
  for (int t = 0; t < NT; ++t) {
    const bool hn = (t + 1) < NT;
    if (hn) {
      STAGE_A(buf ^ 1, t + 1, 0);
      asm volatile("s_waitcnt vmcnt(2)" ::: "memory");
    } else {
      asm volatile("s_waitcnt vmcnt(0)" ::: "memory");
    }
    __builtin_amdgcn_s_barrier();
    PHASE(0);
    __builtin_amdgcn_s_barrier();
    if (hn) {
      if constexpr (FM == 8) STAGE_A(buf ^ 1, t + 1, 1);
      else                   STAGE_B(buf ^ 1, t + 1, 0);
    }
    PHASE(1);
    __builtin_amdgcn_s_barrier();
    if (hn) {
      if constexpr (FM == 8) STAGE_B(buf ^ 1, t + 1, 0);
      else                   STAGE_B(buf ^ 1, t + 1, 1);
    }
    PHASE(2);
    __builtin_amdgcn_s_barrier();
    if (hn) {
      if constexpr (FM == 8) STAGE_B(buf ^ 1, t + 1, 1);
    }
    PHASE(3);
    __builtin_amdgcn_s_barrier();
    buf ^= 1;
  }

  // ---------------- epilogue
  if constexpr (ROPE) {
    const int colbase = n0 + wc * 64 + fr;
#pragma unroll
    for (int i = 0; i < FM; ++i) {
      const int row = m0 + wr * FM * 16 + i * 16 + fq * 4;
      const int s0 = row & 2047;
#pragma unroll
      for (int j = 0; j < 2; ++j) {
        const int col = colbase + j * 16;          // d' = col & 63 in [0,32)
        const bool rot = col < 2560;
        const float scale = (col < 2048) ? 0.18033688011112042f : 1.0f;
        const int dp = col & 63;
#pragma unroll
        for (int v = 0; v < 4; ++v) {
          const float a  = acc[i][j][v];
          const float b2 = acc[i][j + 2][v];
          float o1 = a, o2 = b2;
          if (rot) {
            const float2 cs = ctab[(s0 + v) * 32 + dp];
            o1 = (a * cs.x - b2 * cs.y) * scale;
            o2 = (a * cs.y + b2 * cs.x) * scale;
          }
          ((unsigned short*)Cv)[(size_t)(row + v) * N + col]      = f2bf(o1);
          ((unsigned short*)Cv)[(size_t)(row + v) * N + col + 32] = f2bf(o2);
        }
      }
    }
  } else {
#pragma unroll
    for (int i = 0; i < FM; ++i) {
      const int row = m0 + wr * FM * 16 + i * 16 + fq * 4;
#pragma unroll
      for (int j = 0; j < 4; ++j) {
        const int col = n0 + wc * 64 + j * 16 + fr;
#pragma unroll
        for (int v = 0; v < 4; ++v) {
          if (OUT_BF16) ((unsigned short*)Cv)[(size_t)(row + v) * N + col] = f2bf(acc[i][j][v]);
          else          ((float*)Cv)[(size_t)(row + v) * N + col] = acc[i][j][v];
        }
      }
    }
  }
#undef STAGE_A
#undef STAGE_B
#undef PHASE
}

// ---------------------------------------------------------------- flash attention (round-5 structure, measured 126us)
// Grid (S/256, H=32, B=2), 512 threads (8 waves), 32 q-rows/wave, KBLK=64.
__global__ __launch_bounds__(512, 4) void flash_attn(const unsigned short* __restrict__ qkv,
                                                     unsigned short* __restrict__ out) {
  __shared__ __align__(16) char K_sh[2 * 8192];
  __shared__ __align__(16) char V_sh[2 * 8192];
  __shared__ __align__(16) char P_sh[8 * 4096];

  const int tid = threadIdx.x;
  const int wave = tid >> 6, lane = tid & 63;
  const int fq = lane >> 4, fr = lane & 15;
  const int b = blockIdx.z, h = blockIdx.y;
  const int qt = gridDim.x - 1 - blockIdx.x;       // long blocks first
  const int kvh = h >> 2;
  const int q0 = qt * 256;
  const int wq0 = q0 + wave * 32;
  char* Pw = P_sh + wave * 4096;

  bf16x8 qreg[2][2];
#pragma unroll
  for (int qf = 0; qf < 2; ++qf)
#pragma unroll
    for (int kk = 0; kk < 2; ++kk)
      qreg[qf][kk] = *(const bf16x8*)(qkv + (size_t)(b * 2048 + wq0 + qf * 16 + fr) * 3072
                                      + h * 64 + kk * 32 + fq * 8);

  f32x4 o_acc[4][2];
  float m_run[2], l_run[2];
#pragma unroll
  for (int dc = 0; dc < 4; ++dc) { o_acc[dc][0] = f32x4_zero(); o_acc[dc][1] = f32x4_zero(); }
  m_run[0] = m_run[1] = -1e30f;
  l_run[0] = l_run[1] = 0.f;

  const char* kgbase = (const char*)qkv + (size_t)(b * 2048) * 6144 + 4096 + kvh * 128;
  const unsigned short* vgbase = qkv + (size_t)(b * 2048) * 3072 + 2560 + kvh * 64;
  const int nsteps = (q0 + 256) >> 6;

  const int vk2 = (tid >> 3) << 1;
  const int vc0 = (tid & 7) << 3;
  const int kt = tid - 256;

  {
    if (wave < 4) {
      bf16x8 vv0 = *(const bf16x8*)(vgbase + (size_t)vk2 * 3072 + vc0);
      bf16x8 vv1 = *(const bf16x8*)(vgbase + (size_t)(vk2 + 1) * 3072 + vc0);
#pragma unroll
      for (int j = 0; j < 8; ++j) {
        const int d = vc0 + j;
        const int G = ((d & 7) ^ (d >> 3)) & 7;
        unsigned int w2 = ((unsigned int)(unsigned short)vv0[j]) |
                          (((unsigned int)(unsigned short)vv1[j]) << 16);
        *(unsigned int*)(V_sh + (d << 7) + ((vk2 << 1) ^ (G << 4))) = w2;
      }
    } else {
#pragma unroll
      for (int ld = 0; ld < 2; ++ld) {
        const int row = (kt >> 3) + (ld << 5);
        const int cb = ((kt & 7) << 4) ^ ((row & 7) << 4);
        __builtin_amdgcn_global_load_lds(GPTR(kgbase + (size_t)row * 6144 + cb),
                                         LPTR(K_sh + kt * 16 + ld * 4096), 16, 0, 0);
      }
    }
  }
  __syncthreads();

  int buf = 0;
  for (int st = 0; st < nsteps; ++st) {
    const int k0 = st << 6;
    const bool has_next = (st + 1) < nsteps;
    bf16x8 vv0, vv1;
    if (has_next) {
      const int k0n = k0 + 64;
      if (wave < 4) {
        vv0 = *(const bf16x8*)(vgbase + (size_t)(k0n + vk2) * 3072 + vc0);
        vv1 = *(const bf16x8*)(vgbase + (size_t)(k0n + vk2 + 1) * 3072 + vc0);
      } else {
        char* Kn = K_sh + (buf ^ 1) * 8192;
#pragma unroll
        for (int ld = 0; ld < 2; ++ld) {
          const int row = (kt >> 3) + (ld << 5);
          const int cb = ((kt & 7) << 4) ^ ((row & 7) << 4);
          __builtin_amdgcn_global_load_lds(GPTR(kgbase + (size_t)(k0n + row) * 6144 + cb),
                                           LPTR(Kn + kt * 16 + ld * 4096), 16, 0, 0);
        }
      }
    }

    if (k0 <= wq0 + 31) {
      const char* Kb = K_sh + buf * 8192;
      const char* Vb = V_sh + buf * 8192;
      f32x4 s[2][4];
#pragma unroll
      for (int qf = 0; qf < 2; ++qf)
#pragma unroll
        for (int kf = 0; kf < 4; ++kf) s[qf][kf] = f32x4_zero();
#pragma unroll
      for (int kf = 0; kf < 4; ++kf) {
        const int krow = kf * 16 + fr;
        const int swz = (krow & 7) << 4;
        bf16x8 ka = *(const bf16x8*)(Kb + krow * 128 + ((fq * 16) ^ swz));
        bf16x8 kb = *(const bf16x8*)(Kb + krow * 128 + ((64 + fq * 16) ^ swz));
#pragma unroll
        for (int qf = 0; qf < 2; ++qf) {
          s[qf][kf] = __builtin_amdgcn_mfma_f32_16x16x32_bf16(ka, qreg[qf][0], s[qf][kf], 0, 0, 0);
          s[qf][kf] = __builtin_amdgcn_mfma_f32_16x16x32_bf16(kb, qreg[qf][1], s[qf][kf], 0, 0, 0);
        }
      }
      if (k0 + 63 > wq0) {
#pragma unroll
        for (int qf = 0; qf < 2; ++qf) {
          const int q = wq0 + qf * 16 + fr;
#pragma unroll
          for (int kf = 0; kf < 4; ++kf)
#pragma unroll
            for (int v = 0; v < 4; ++v) {
              const int key = k0 + kf * 16 + fq * 4 + v;
              if (key > q) s[qf][kf][v] = -1e30f;
            }
        }
      }
#pragma unroll
      for (int qf = 0; qf < 2; ++qf) {
        float t = s[qf][0][0];
#pragma unroll
        for (int kf = 0; kf < 4; ++kf)
#pragma unroll
          for (int v = 0; v < 4; ++v) t = fmaxf(t, s[qf][kf][v]);
        t = fmaxf(t, __shfl_xor(t, 16));
        t = fmaxf(t, __shfl_xor(t, 32));
        const float mo = m_run[qf];
        const float mn = fmaxf(mo, t);
        const float sc = __builtin_amdgcn_exp2f(mo - mn);
        m_run[qf] = mn;
        float ps = 0.f;
#pragma unroll
        for (int kf = 0; kf < 4; ++kf)
#pragma unroll
          for (int v = 0; v < 4; ++v) {
            const float p = __builtin_amdgcn_exp2f(s[qf][kf][v] - mn);
            s[qf][kf][v] = p;
            ps += p;
          }
        ps += __shfl_xor(ps, 16);
        ps += __shfl_xor(ps, 32);
        l_run[qf] = l_run[qf] * sc + ps;
#pragma unroll
        for (int dc = 0; dc < 4; ++dc) o_acc[dc][qf] *= sc;
        const int r = qf * 16 + fr;
        const int rswz = (r & 7) << 4;
#pragma unroll
        for (int kf = 0; kf < 4; ++kf) {
          uint2 w2;
          w2.x = cvt_pk_bf16(s[qf][kf][0], s[qf][kf][1]);
          w2.y = cvt_pk_bf16(s[qf][kf][2], s[qf][kf][3]);
          *(uint2*)(Pw + r * 128 + ((kf * 32 + fq * 8) ^ rswz)) = w2;
        }
      }
      asm volatile("s_waitcnt lgkmcnt(0)" ::: "memory");
      __builtin_amdgcn_sched_barrier(0);
      const int fswz = (fr & 7) << 4;
#pragma unroll
      for (int kk = 0; kk < 2; ++kk) {
        bf16x8 pa0 = *(const bf16x8*)(Pw + fr * 128 + ((kk * 64 + fq * 16) ^ fswz));
        bf16x8 pa1 = *(const bf16x8*)(Pw + (16 + fr) * 128 + ((kk * 64 + fq * 16) ^ fswz));
#pragma unroll
        for (int dc = 0; dc < 4; ++dc) {
          const int d = dc * 16 + fr;
          const int G = ((d & 7) ^ (d >> 3)) & 7;
          bf16x8 vt = *(const bf16x8*)(Vb + d * 128 + ((kk * 64 + fq * 16) ^ (G << 4)));
          o_acc[dc][0] = __builtin_amdgcn_mfma_f32_16x16x32_bf16(vt, pa0, o_acc[dc][0], 0, 0, 0);
          o_acc[dc][1] = __builtin_amdgcn_mfma_f32_16x16x32_bf16(vt, pa1, o_acc[dc][1], 0, 0, 0);
        }
      }
    }

    if (has_next && wave < 4) {
      char* Vn = V_sh + (buf ^ 1) * 8192;
#pragma unroll
      for (int j = 0; j < 8; ++j) {
        const int d = vc0 + j;
        const int G = ((d & 7) ^ (d >> 3)) & 7;
        unsigned int w2 = ((unsigned int)(unsigned short)vv0[j]) |
                          (((unsigned int)(unsigned short)vv1[j]) << 16);
        *(unsigned int*)(Vn + (d << 7) + ((vk2 << 1) ^ (G << 4))) = w2;
      }
    }
    __syncthreads();
    buf ^= 1;
  }

#pragma unroll
  for (int qf = 0; qf < 2; ++qf) {
    const float inv = 1.0f / l_run[qf];
    const size_t row = (size_t)(b * 2048 + wq0 + qf * 16 + fr);
#pragma unroll
    for (int dc = 0; dc < 4; ++dc) {
      u16x4 o;
#pragma unroll
      for (int v = 0; v < 4; ++v) o[v] = f2bf(o_acc[dc][qf][v] * inv);
      *(u16x4*)(out + row * 2048 + h * 64 + dc * 16 + fq * 4) = o;
    }
  }
}

// ---------------------------------------------------------------- launch
extern "C" void kernel_launch(void* const* d_in, const int* in_sizes, int n_in,
                              void* d_out, int out_size, void* d_ws, size_t ws_size,
                              hipStream_t stream) {
  (void)in_sizes; (void)n_in; (void)out_size; (void)ws_size;
  const float* x  = (const float*)d_in[0];
  const float* wq = (const float*)d_in[1];
  const float* wk = (const float*)d_in[2];
  const float* wv = (const float*)d_in[3];
  const float* wo = (const float*)d_in[4];

  char* wsb = (char*)d_ws;
  unsigned short* xb     = (unsigned short*)(wsb);
  unsigned short* attn_o = xb;
  unsigned short* wqkvb  = (unsigned short*)(wsb + 16777216);
  unsigned short* wob    = (unsigned short*)(wsb + 29360128);
  unsigned short* qkv    = (unsigned short*)(wsb + 37748736);
  float2* ctab           = (float2*)(wsb + 62914560);   // 2048*32*8B = 512KB

  convert_all<<<2048, 256, 0, stream>>>(x, wq, wk, wv, wo, xb, wqkvb, wob, ctab);

  // qkv = x @ [wq;wk;wv]^T (+ fused RoPE) : M=4096, N=3072, K=2048
  // FM=4 (BM=128): 32x12 = 384 blocks -> fills all 256 CUs (vs 192 blocks = 75%)
  gemm8p<4, 1, 1><<<384, 512, 0, stream>>>(xb, wqkvb, (void*)qkv, 4096, 3072, 2048, 12, ctab);

  flash_attn<<<dim3(8, 32, 2), 512, 0, stream>>>(qkv, attn_o);

  // out = attn @ wo^T : M=4096, N=2048, K=2048 ; 256 blocks (32x8)
  gemm8p<4, 0, 0><<<256, 512, 0, stream>>>(attn_o, wob, d_out, 4096, 2048, 2048, 8, nullptr);
}

// Round 16
// 248.484 us; speedup vs baseline: 1.0781x; 1.0781x over previous
//
#include <hip/hip_runtime.h>

typedef __attribute__((ext_vector_type(8))) short bf16x8;
typedef __attribute__((ext_vector_type(4))) float f32x4;
typedef __attribute__((ext_vector_type(4))) unsigned short u16x4;

#define GPTR(p) (const __attribute__((address_space(1))) void*)(p)
#define LPTR(p) (__attribute__((address_space(3))) void*)(p)

static __device__ __forceinline__ unsigned short f2bf(float f) {
  union { float f; unsigned int u; } x; x.f = f;
  unsigned int u = x.u;
  unsigned int r = (u + 0x7fffu + ((u >> 16) & 1u)) >> 16;
  return (unsigned short)r;
}
static __device__ __forceinline__ float bf2f(unsigned short h) {
  union { unsigned int u; float f; } x; x.u = ((unsigned int)h) << 16;
  return x.f;
}
static __device__ __forceinline__ f32x4 f32x4_zero() {
  f32x4 z = {0.f, 0.f, 0.f, 0.f}; return z;
}
static __device__ __forceinline__ unsigned int cvt_pk_bf16(float lo, float hi) {
  unsigned int r;
  asm("v_cvt_pk_bf16_f32 %0, %1, %2" : "=v"(r) : "v"(lo), "v"(hi));
  return r;
}

// ---------------------------------------------------------------- converts + RoPE table, one launch
__global__ void convert_all(const float* __restrict__ x,  const float* __restrict__ wq,
                            const float* __restrict__ wk, const float* __restrict__ wv,
                            const float* __restrict__ wo,
                            unsigned short* __restrict__ xb,
                            unsigned short* __restrict__ wqkvb,
                            unsigned short* __restrict__ wob,
                            float2* __restrict__ ctab) {
  const int stride = gridDim.x * blockDim.x;
  for (int i = blockIdx.x * blockDim.x + threadIdx.x; i < 4784128; i += stride) {
    if (i >= 4718592) {
      const int t = i - 4718592;         // 65536 table entries
      const int s = t >> 5, d = t & 31;
      float invf = exp2f(-(float)d * (13.287712379549449f / 32.0f));
      float a = (float)s * invf;
      ctab[t] = make_float2(cosf(a), sinf(a));
      continue;
    }
    const float* src; unsigned short* dst; int off;
    if (i < 2097152)      { src = x;  dst = xb;              off = i; }
    else if (i < 3145728) { src = wq; dst = wqkvb;           off = i - 2097152; }
    else if (i < 3407872) { src = wk; dst = wqkvb + 4194304; off = i - 3145728; }
    else if (i < 3670016) { src = wv; dst = wqkvb + 5242880; off = i - 3407872; }
    else                  { src = wo; dst = wob;             off = i - 3670016; }
    float4 v = ((const float4*)src)[off];
    u16x4 o;
    o.x = f2bf(v.x); o.y = f2bf(v.y); o.z = f2bf(v.z); o.w = f2bf(v.w);
    *(u16x4*)(dst + (size_t)off * 4) = o;
  }
}

// ---------------------------------------------------------------- 8-wave 4-phase GEMM C = A @ B^T
template<int FM, int OUT_BF16, int ROPE>
__global__ __launch_bounds__(512, 2) void gemm8p(const unsigned short* __restrict__ A,
                                                 const unsigned short* __restrict__ B,
                                                 void* __restrict__ Cv,
                                                 int M, int N, int K, int nbx,
                                                 const float2* __restrict__ ctab) {
  constexpr int BM = FM * 32;
  constexpr int MH = FM / 2;
  constexpr int ABYTES = BM * 128;      // per buffer
  constexpr int BBYTES = 256 * 128;
  __shared__ __align__(16) char lds_all[2 * ABYTES + 2 * BBYTES];
  char* lsA = lds_all;
  char* lsB = lds_all + 2 * ABYTES;

  const int tid = threadIdx.x;
  const int wave = tid >> 6, lane = tid & 63;
  const int fq = lane >> 4, fr = lane & 15;
  const int wr = wave >> 2, wc = wave & 3;

  const int nwg = gridDim.x;
  const int q8 = nwg >> 3;
  const int sw = (blockIdx.x & 7) * q8 + (blockIdx.x >> 3);
  const int by = sw / nbx;
  const int bx = sw - by * nbx;
  const int m0 = by * BM, n0 = bx * 256;

  const int arow = tid >> 3;
  const int scol = (((tid & 7) ^ (arow & 7)) << 4);   // pre-swizzled source col byte

#define STAGE_A(bufv, kt, h)                                                                  \
  do {                                                                                        \
    const char* src_ = (const char*)A + ((size_t)(m0 + (h) * 128 + arow) * K + (kt) * 64) * 2 + scol; \
    char* dst_ = lsA + (bufv) * ABYTES + (h) * 16384 + tid * 16;                              \
    __builtin_amdgcn_global_load_lds(GPTR(src_), LPTR(dst_), 16, 0, 0);                       \
    __builtin_amdgcn_global_load_lds(GPTR(src_ + (size_t)64 * K * 2), LPTR(dst_ + 8192), 16, 0, 0); \
  } while (0)
#define STAGE_B(bufv, kt, h)                                                                  \
  do {                                                                                        \
    const char* src_ = (const char*)B + ((size_t)(n0 + (h) * 128 + arow) * K + (kt) * 64) * 2 + scol; \
    char* dst_ = lsB + (bufv) * BBYTES + (h) * 16384 + tid * 16;                              \
    __builtin_amdgcn_global_load_lds(GPTR(src_), LPTR(dst_), 16, 0, 0);                       \
    __builtin_amdgcn_global_load_lds(GPTR(src_ + (size_t)64 * K * 2), LPTR(dst_ + 8192), 16, 0, 0); \
  } while (0)

  f32x4 acc[FM][4];
#pragma unroll
  for (int i = 0; i < FM; ++i)
#pragma unroll
    for (int j = 0; j < 4; ++j) acc[i][j] = f32x4_zero();

#define PHASE(p)                                                                              \
  do {                                                                                        \
    constexpr int mh = (p) >> 1, nh = (p) & 1;                                                \
    bf16x8 af[MH][2], bfv[2][2];                                                              \
    _Pragma("unroll") for (int m = 0; m < MH; ++m) {                                          \
      const int rowA = wr * FM * 16 + mh * MH * 16 + m * 16 + fr;                             \
      const char* pa = lsA + buf * ABYTES + (rowA >> 7) * 16384 + (rowA & 127) * 128;         \
      const int sz = (rowA & 7) << 4;                                                         \
      af[m][0] = *(const bf16x8*)(pa + ((fq * 16) ^ sz));                                     \
      af[m][1] = *(const bf16x8*)(pa + ((64 + fq * 16) ^ sz));                                \
    }                                                                                         \
    _Pragma("unroll") for (int n = 0; n < 2; ++n) {                                           \
      const int rowB = wc * 64 + nh * 32 + n * 16 + fr;                                       \
      const char* pb = lsB + buf * BBYTES + (rowB >> 7) * 16384 + (rowB & 127) * 128;         \
      const int sz = (rowB & 7) << 4;                                                         \
      bfv[n][0] = *(const bf16x8*)(pb + ((fq * 16) ^ sz));                                    \
      bfv[n][1] = *(const bf16x8*)(pb + ((64 + fq * 16) ^ sz));                               \
    }                                                                                         \
    asm volatile("s_waitcnt lgkmcnt(0)" ::: "memory");                                        \
    __builtin_amdgcn_sched_barrier(0);                                                        \
    __builtin_amdgcn_s_setprio(1);                                                            \
    _Pragma("unroll") for (int m = 0; m < MH; ++m)                                            \
      _Pragma("unroll") for (int n = 0; n < 2; ++n) {                                         \
        acc[mh * MH + m][nh * 2 + n] =                                                        \
            __builtin_amdgcn_mfma_f32_16x16x32_bf16(af[m][0], bfv[n][0], acc[mh * MH + m][nh * 2 + n], 0, 0, 0); \
        acc[mh * MH + m][nh * 2 + n] =                                                        \
            __builtin_amdgcn_mfma_f32_16x16x32_bf16(af[m][1], bfv[n][1], acc[mh * MH + m][nh * 2 + n], 0, 0, 0); \
      }                                                                                       \
    __builtin_amdgcn_s_setprio(0);                                                            \
  } while (0)

  const int NT = K >> 6;

  STAGE_A(0, 0, 0);
  if constexpr (FM == 8) STAGE_A(0, 0, 1);
  STAGE_B(0, 0, 0);
  STAGE_B(0, 0, 1);
  asm volatile("s_waitcnt vmcnt(0)" ::: "memory");
  __builtin_amdgcn_s_barrier();

  int buf = 0;
  for (int t = 0; t < NT; ++t) {
    const bool hn = (t + 1) < NT;
    if (hn) {
      STAGE_A(buf ^ 1, t + 1, 0);
      asm volatile("s_waitcnt vmcnt(2)" ::: "memory");
    } else {
      asm volatile("s_waitcnt vmcnt(0)" ::: "memory");
    }
    __builtin_amdgcn_s_barrier();
    PHASE(0);
    __builtin_amdgcn_s_barrier();
    if (hn) {
      if constexpr (FM == 8) STAGE_A(buf ^ 1, t + 1, 1);
      else                   STAGE_B(buf ^ 1, t + 1, 0);
    }
    PHASE(1);
    __builtin_amdgcn_s_barrier();
    if (hn) {
      if constexpr (FM == 8) STAGE_B(buf ^ 1, t + 1, 0);
      else                   STAGE_B(buf ^ 1, t + 1, 1);
    }
    PHASE(2);
    __builtin_amdgcn_s_barrier();
    if (hn) {
      if constexpr (FM == 8) STAGE_B(buf ^ 1, t + 1, 1);
    }
    PHASE(3);
    __builtin_amdgcn_s_barrier();
    buf ^= 1;
  }

  // ---------------- epilogue
  if constexpr (ROPE) {
    const int colbase = n0 + wc * 64 + fr;
#pragma unroll
    for (int i = 0; i < FM; ++i) {
      const int row = m0 + wr * FM * 16 + i * 16 + fq * 4;
      const int s0 = row & 2047;
#pragma unroll
      for (int j = 0; j < 2; ++j) {
        const int col = colbase + j * 16;          // d' = col & 63 in [0,32)
        const bool rot = col < 2560;
        const float scale = (col < 2048) ? 0.18033688011112042f : 1.0f;
        const int dp = col & 63;
#pragma unroll
        for (int v = 0; v < 4; ++v) {
          const float a  = acc[i][j][v];
          const float b2 = acc[i][j + 2][v];
          float o1 = a, o2 = b2;
          if (rot) {
            const float2 cs = ctab[(s0 + v) * 32 + dp];
            o1 = (a * cs.x - b2 * cs.y) * scale;
            o2 = (a * cs.y + b2 * cs.x) * scale;
          }
          ((unsigned short*)Cv)[(size_t)(row + v) * N + col]      = f2bf(o1);
          ((unsigned short*)Cv)[(size_t)(row + v) * N + col + 32] = f2bf(o2);
        }
      }
    }
  } else {
#pragma unroll
    for (int i = 0; i < FM; ++i) {
      const int row = m0 + wr * FM * 16 + i * 16 + fq * 4;
#pragma unroll
      for (int j = 0; j < 4; ++j) {
        const int col = n0 + wc * 64 + j * 16 + fr;
#pragma unroll
        for (int v = 0; v < 4; ++v) {
          if (OUT_BF16) ((unsigned short*)Cv)[(size_t)(row + v) * N + col] = f2bf(acc[i][j][v]);
          else          ((float*)Cv)[(size_t)(row + v) * N + col] = acc[i][j][v];
        }
      }
    }
  }
#undef STAGE_A
#undef STAGE_B
#undef PHASE
}

// ---------------------------------------------------------------- flash attention (round-5 structure, measured 126us)
// Grid (S/256, H=32, B=2), 512 threads (8 waves), 32 q-rows/wave, KBLK=64.
__global__ __launch_bounds__(512, 4) void flash_attn(const unsigned short* __restrict__ qkv,
                                                     unsigned short* __restrict__ out) {
  __shared__ __align__(16) char K_sh[2 * 8192];
  __shared__ __align__(16) char V_sh[2 * 8192];
  __shared__ __align__(16) char P_sh[8 * 4096];

  const int tid = threadIdx.x;
  const int wave = tid >> 6, lane = tid & 63;
  const int fq = lane >> 4, fr = lane & 15;
  const int b = blockIdx.z, h = blockIdx.y;
  const int qt = gridDim.x - 1 - blockIdx.x;       // long blocks first
  const int kvh = h >> 2;
  const int q0 = qt * 256;
  const int wq0 = q0 + wave * 32;
  char* Pw = P_sh + wave * 4096;

  bf16x8 qreg[2][2];
#pragma unroll
  for (int qf = 0; qf < 2; ++qf)
#pragma unroll
    for (int kk = 0; kk < 2; ++kk)
      qreg[qf][kk] = *(const bf16x8*)(qkv + (size_t)(b * 2048 + wq0 + qf * 16 + fr) * 3072
                                      + h * 64 + kk * 32 + fq * 8);

  f32x4 o_acc[4][2];
  float m_run[2], l_run[2];
#pragma unroll
  for (int dc = 0; dc < 4; ++dc) { o_acc[dc][0] = f32x4_zero(); o_acc[dc][1] = f32x4_zero(); }
  m_run[0] = m_run[1] = -1e30f;
  l_run[0] = l_run[1] = 0.f;

  const char* kgbase = (const char*)qkv + (size_t)(b * 2048) * 6144 + 4096 + kvh * 128;
  const unsigned short* vgbase = qkv + (size_t)(b * 2048) * 3072 + 2560 + kvh * 64;
  const int nsteps = (q0 + 256) >> 6;

  const int vk2 = (tid >> 3) << 1;
  const int vc0 = (tid & 7) << 3;
  const int kt = tid - 256;

  {
    if (wave < 4) {
      bf16x8 vv0 = *(const bf16x8*)(vgbase + (size_t)vk2 * 3072 + vc0);
      bf16x8 vv1 = *(const bf16x8*)(vgbase + (size_t)(vk2 + 1) * 3072 + vc0);
#pragma unroll
      for (int j = 0; j < 8; ++j) {
        const int d = vc0 + j;
        const int G = ((d & 7) ^ (d >> 3)) & 7;
        unsigned int w2 = ((unsigned int)(unsigned short)vv0[j]) |
                          (((unsigned int)(unsigned short)vv1[j]) << 16);
        *(unsigned int*)(V_sh + (d << 7) + ((vk2 << 1) ^ (G << 4))) = w2;
      }
    } else {
#pragma unroll
      for (int ld = 0; ld < 2; ++ld) {
        const int row = (kt >> 3) + (ld << 5);
        const int cb = ((kt & 7) << 4) ^ ((row & 7) << 4);
        __builtin_amdgcn_global_load_lds(GPTR(kgbase + (size_t)row * 6144 + cb),
                                         LPTR(K_sh + kt * 16 + ld * 4096), 16, 0, 0);
      }
    }
  }
  __syncthreads();

  int buf = 0;
  for (int st = 0; st < nsteps; ++st) {
    const int k0 = st << 6;
    const bool has_next = (st + 1) < nsteps;
    bf16x8 vv0, vv1;
    if (has_next) {
      const int k0n = k0 + 64;
      if (wave < 4) {
        vv0 = *(const bf16x8*)(vgbase + (size_t)(k0n + vk2) * 3072 + vc0);
        vv1 = *(const bf16x8*)(vgbase + (size_t)(k0n + vk2 + 1) * 3072 + vc0);
      } else {
        char* Kn = K_sh + (buf ^ 1) * 8192;
#pragma unroll
        for (int ld = 0; ld < 2; ++ld) {
          const int row = (kt >> 3) + (ld << 5);
          const int cb = ((kt & 7) << 4) ^ ((row & 7) << 4);
          __builtin_amdgcn_global_load_lds(GPTR(kgbase + (size_t)(k0n + row) * 6144 + cb),
                                           LPTR(Kn + kt * 16 + ld * 4096), 16, 0, 0);
        }
      }
    }

    if (k0 <= wq0 + 31) {
      const char* Kb = K_sh + buf * 8192;
      const char* Vb = V_sh + buf * 8192;
      f32x4 s[2][4];
#pragma unroll
      for (int qf = 0; qf < 2; ++qf)
#pragma unroll
        for (int kf = 0; kf < 4; ++kf) s[qf][kf] = f32x4_zero();
#pragma unroll
      for (int kf = 0; kf < 4; ++kf) {
        const int krow = kf * 16 + fr;
        const int swz = (krow & 7) << 4;
        bf16x8 ka = *(const bf16x8*)(Kb + krow * 128 + ((fq * 16) ^ swz));
        bf16x8 kb = *(const bf16x8*)(Kb + krow * 128 + ((64 + fq * 16) ^ swz));
#pragma unroll
        for (int qf = 0; qf < 2; ++qf) {
          s[qf][kf] = __builtin_amdgcn_mfma_f32_16x16x32_bf16(ka, qreg[qf][0], s[qf][kf], 0, 0, 0);
          s[qf][kf] = __builtin_amdgcn_mfma_f32_16x16x32_bf16(kb, qreg[qf][1], s[qf][kf], 0, 0, 0);
        }
      }
      if (k0 + 63 > wq0) {
#pragma unroll
        for (int qf = 0; qf < 2; ++qf) {
          const int q = wq0 + qf * 16 + fr;
#pragma unroll
          for (int kf = 0; kf < 4; ++kf)
#pragma unroll
            for (int v = 0; v < 4; ++v) {
              const int key = k0 + kf * 16 + fq * 4 + v;
              if (key > q) s[qf][kf][v] = -1e30f;
            }
        }
      }
#pragma unroll
      for (int qf = 0; qf < 2; ++qf) {
        float t = s[qf][0][0];
#pragma unroll
        for (int kf = 0; kf < 4; ++kf)
#pragma unroll
          for (int v = 0; v < 4; ++v) t = fmaxf(t, s[qf][kf][v]);
        t = fmaxf(t, __shfl_xor(t, 16));
        t = fmaxf(t, __shfl_xor(t, 32));
        const float mo = m_run[qf];
        const float mn = fmaxf(mo, t);
        const float sc = __builtin_amdgcn_exp2f(mo - mn);
        m_run[qf] = mn;
        float ps = 0.f;
#pragma unroll
        for (int kf = 0; kf < 4; ++kf)
#pragma unroll
          for (int v = 0; v < 4; ++v) {
            const float p = __builtin_amdgcn_exp2f(s[qf][kf][v] - mn);
            s[qf][kf][v] = p;
            ps += p;
          }
        ps += __shfl_xor(ps, 16);
        ps += __shfl_xor(ps, 32);
        l_run[qf] = l_run[qf] * sc + ps;
#pragma unroll
        for (int dc = 0; dc < 4; ++dc) o_acc[dc][qf] *= sc;
        const int r = qf * 16 + fr;
        const int rswz = (r & 7) << 4;
#pragma unroll
        for (int kf = 0; kf < 4; ++kf) {
          uint2 w2;
          w2.x = cvt_pk_bf16(s[qf][kf][0], s[qf][kf][1]);
          w2.y = cvt_pk_bf16(s[qf][kf][2], s[qf][kf][3]);
          *(uint2*)(Pw + r * 128 + ((kf * 32 + fq * 8) ^ rswz)) = w2;
        }
      }
      asm volatile("s_waitcnt lgkmcnt(0)" ::: "memory");
      __builtin_amdgcn_sched_barrier(0);
      const int fswz = (fr & 7) << 4;
#pragma unroll
      for (int kk = 0; kk < 2; ++kk) {
        bf16x8 pa0 = *(const bf16x8*)(Pw + fr * 128 + ((kk * 64 + fq * 16) ^ fswz));
        bf16x8 pa1 = *(const bf16x8*)(Pw + (16 + fr) * 128 + ((kk * 64 + fq * 16) ^ fswz));
#pragma unroll
        for (int dc = 0; dc < 4; ++dc) {
          const int d = dc * 16 + fr;
          const int G = ((d & 7) ^ (d >> 3)) & 7;
          bf16x8 vt = *(const bf16x8*)(Vb + d * 128 + ((kk * 64 + fq * 16) ^ (G << 4)));
          o_acc[dc][0] = __builtin_amdgcn_mfma_f32_16x16x32_bf16(vt, pa0, o_acc[dc][0], 0, 0, 0);
          o_acc[dc][1] = __builtin_amdgcn_mfma_f32_16x16x32_bf16(vt, pa1, o_acc[dc][1], 0, 0, 0);
        }
      }
    }

    if (has_next && wave < 4) {
      char* Vn = V_sh + (buf ^ 1) * 8192;
#pragma unroll
      for (int j = 0; j < 8; ++j) {
        const int d = vc0 + j;
        const int G = ((d & 7) ^ (d >> 3)) & 7;
        unsigned int w2 = ((unsigned int)(unsigned short)vv0[j]) |
                          (((unsigned int)(unsigned short)vv1[j]) << 16);
        *(unsigned int*)(Vn + (d << 7) + ((vk2 << 1) ^ (G << 4))) = w2;
      }
    }
    __syncthreads();
    buf ^= 1;
  }

#pragma unroll
  for (int qf = 0; qf < 2; ++qf) {
    const float inv = 1.0f / l_run[qf];
    const size_t row = (size_t)(b * 2048 + wq0 + qf * 16 + fr);
#pragma unroll
    for (int dc = 0; dc < 4; ++dc) {
      u16x4 o;
#pragma unroll
      for (int v = 0; v < 4; ++v) o[v] = f2bf(o_acc[dc][qf][v] * inv);
      *(u16x4*)(out + row * 2048 + h * 64 + dc * 16 + fq * 4) = o;
    }
  }
}

// ---------------------------------------------------------------- launch
extern "C" void kernel_launch(void* const* d_in, const int* in_sizes, int n_in,
                              void* d_out, int out_size, void* d_ws, size_t ws_size,
                              hipStream_t stream) {
  (void)in_sizes; (void)n_in; (void)out_size; (void)ws_size;
  const float* x  = (const float*)d_in[0];
  const float* wq = (const float*)d_in[1];
  const float* wk = (const float*)d_in[2];
  const float* wv = (const float*)d_in[3];
  const float* wo = (const float*)d_in[4];

  char* wsb = (char*)d_ws;
  unsigned short* xb     = (unsigned short*)(wsb);
  unsigned short* attn_o = xb;
  unsigned short* wqkvb  = (unsigned short*)(wsb + 16777216);
  unsigned short* wob    = (unsigned short*)(wsb + 29360128);
  unsigned short* qkv    = (unsigned short*)(wsb + 37748736);
  float2* ctab           = (float2*)(wsb + 62914560);   // 2048*32*8B = 512KB

  convert_all<<<2048, 256, 0, stream>>>(x, wq, wk, wv, wo, xb, wqkvb, wob, ctab);

  // qkv = x @ [wq;wk;wv]^T (+ fused RoPE) : M=4096, N=3072, K=2048 ; 192 blocks (16x12)
  gemm8p<8, 1, 1><<<192, 512, 0, stream>>>(xb, wqkvb, (void*)qkv, 4096, 3072, 2048, 12, ctab);

  flash_attn<<<dim3(8, 32, 2), 512, 0, stream>>>(qkv, attn_o);

  // out = attn @ wo^T : M=4096, N=2048, K=2048 ; 256 blocks (32x8)
  gemm8p<4, 0, 0><<<256, 512, 0, stream>>>(attn_o, wob, d_out, 4096, 2048, 2048, 8, nullptr);
}